// Round 11
// baseline (979.009 us; speedup 1.0000x reference)
//
#include <hip/hip_runtime.h>
#include <hip/hip_bf16.h>
#include <cstdint>
#include <cstddef>

#define L_SEQ   8192
#define DMODEL  768
#define NHEADS  24
#define DINNER  1536
#define NPROJ   3096      /* 24 * 129 */
#define NPROJP  3200      /* padded weight rows for gload_lds */
#define NTOK    16384
#define RMS_EPS 1.1920929e-07f

typedef __hip_bfloat16 bf16;
typedef __attribute__((ext_vector_type(8))) short bf8v;
typedef __attribute__((ext_vector_type(4))) float f4v;

__device__ __forceinline__ float clampf(float x, float lo, float hi) {
    return fminf(fmaxf(x, lo), hi);
}
__device__ __forceinline__ float bf2f(bf16 v) { return __bfloat162float(v); }
__device__ __forceinline__ bf16  f2bf(float v) { return __float2bfloat16(v); }
__device__ __forceinline__ short f2bs(float v) {
    bf16 b = __float2bfloat16(v);
    return *reinterpret_cast<short*>(&b);
}
__device__ __forceinline__ float bs2f(short v) {
    return __uint_as_float(((unsigned)(unsigned short)v) << 16);
}
__device__ __forceinline__ void st1(float* p, float v) { *p = v; }
__device__ __forceinline__ void st1(bf16* p, float v) { *p = f2bf(v); }
__device__ __forceinline__ void st4(bf16* p, float4 v) {
    p[0] = f2bf(v.x); p[1] = f2bf(v.y); p[2] = f2bf(v.z); p[3] = f2bf(v.w);
}

#define GLOAD16(gsrc, ldst) __builtin_amdgcn_global_load_lds( \
    (const __attribute__((address_space(1))) void*)(gsrc),    \
    (__attribute__((address_space(3))) void*)(ldst), 16, 0, 0)

// ---------------------------------------------------------------- f32 -> bf16 weight conversion
__global__ __launch_bounds__(256) void k_cvt(const float* __restrict__ s,
                                             bf16* __restrict__ d, int n4) {
    int i = blockIdx.x * 256 + threadIdx.x;
    if (i < n4) {
        float4 v = *(const float4*)&s[i * 4];
        st4(&d[i * 4], v);
    }
}
__global__ __launch_bounds__(256) void k_zero(bf16* __restrict__ d, int n) {
    int i = blockIdx.x * 256 + threadIdx.x;
    if (i < n) d[i] = f2bf(0.f);
}

// ---------------------------------------------------------------- RMSNorm (f32 in, bf16 out), all tokens
__global__ __launch_bounds__(256) void k_rmsnorm(const float* __restrict__ hs,
                                                 const float* __restrict__ w,
                                                 bf16* __restrict__ xn) {
    int t = blockIdx.x;
    const float* p = hs + (size_t)t * DMODEL;
    float s = 0.f;
    for (int i = threadIdx.x; i < DMODEL; i += 256) { float v = p[i]; s += v * v; }
    for (int off = 32; off; off >>= 1) s += __shfl_xor(s, off, 64);
    __shared__ float ws4[4];
    int lane = threadIdx.x & 63, wv = threadIdx.x >> 6;
    if (lane == 0) ws4[wv] = s;
    __syncthreads();
    s = ws4[0] + ws4[1] + ws4[2] + ws4[3];
    float r = 1.0f / sqrtf(s * (1.0f / DMODEL) + RMS_EPS);
    bf16* o = xn + (size_t)t * DMODEL;
    for (int i = threadIdx.x; i < DMODEL; i += 256) o[i] = f2bf(p[i] * r * w[i]);
}

// ---------------------------------------------------------------- MFMA GEMM  C[M,N] = A[M,K] @ B[N,K]^T + bias
// 128x128 tile, BK=32, 4 waves, global_load_lds staging, 1 barrier/K-step
// double buffer, L2-supertiled XCD swizzle. Requires gy % 8 == 0 and all
// B rows [n0, n0+127] readable (weights padded).
template <typename TC, int EPI>
__global__ __launch_bounds__(256) void k_mgemm(const bf16* __restrict__ A,
                                               const bf16* __restrict__ B,
                                               const float* __restrict__ bias,
                                               TC* __restrict__ C,
                                               int M, int N, int K,
                                               const float* __restrict__ resid,
                                               const float* __restrict__ gatep) {
    __shared__ short As[2][128 * 32];
    __shared__ short Bs[2][128 * 32];
    int tid = threadIdx.x;
    int lane = tid & 63, w = tid >> 6;

    int gx = gridDim.x, gy = gridDim.y;
    int bid = blockIdx.y * gx + blockIdx.x;
    int xcd = bid & 7, idx = bid >> 3;
    int bys = gy >> 3;
    int gby = bys < 8 ? bys : 8;
    int sg  = idx / (gx * gby);
    int rem = idx - sg * (gx * gby);
    int bx  = rem / gby;
    int byl = rem - bx * gby;
    int by  = xcd * bys + sg * gby + byl;
    int m0 = by * 128, n0 = bx * 128;

    int wm = (w >> 1) << 6, wn = (w & 1) << 6;

    const size_t rowskip = (size_t)16 * K * 2;
    const char* Ag = (const char*)(A + (size_t)(m0 + (w << 5) + (lane >> 2)) * K) + (lane & 3) * 16;
    const char* Bg = (const char*)(B + (size_t)(n0 + (w << 5) + (lane >> 2)) * K) + (lane & 3) * 16;
    short* Al0 = &As[0][(w << 5) * 32];
    short* Bl0 = &Bs[0][(w << 5) * 32];
    short* Al1 = &As[1][(w << 5) * 32];
    short* Bl1 = &Bs[1][(w << 5) * 32];

    f4v acc[4][4];
#pragma unroll
    for (int i = 0; i < 4; ++i)
#pragma unroll
        for (int j = 0; j < 4; ++j) acc[i][j] = (f4v){0.f, 0.f, 0.f, 0.f};

    auto stage = [&](int buf, int k0) {
        size_t kb = (size_t)k0 * 2;
        short* Al = buf ? Al1 : Al0;
        short* Bl = buf ? Bl1 : Bl0;
        GLOAD16(Ag + kb,           Al);
        GLOAD16(Ag + kb + rowskip, Al + 16 * 32);
        GLOAD16(Bg + kb,           Bl);
        GLOAD16(Bg + kb + rowskip, Bl + 16 * 32);
    };

    stage(0, 0);
    int cur = 0;
    int row16 = lane & 15, kg = (lane >> 4) << 3;
    for (int k0 = 0; k0 < K; k0 += 32) {
        __syncthreads();
        if (k0 + 32 < K) stage(cur ^ 1, k0 + 32);
        const short* Ab = As[cur];
        const short* Bb = Bs[cur];
        bf8v af[4], bfv[4];
#pragma unroll
        for (int fm = 0; fm < 4; ++fm)
            af[fm] = *(const bf8v*)&Ab[(wm + (fm << 4) + row16) * 32 + kg];
#pragma unroll
        for (int fn = 0; fn < 4; ++fn)
            bfv[fn] = *(const bf8v*)&Bb[(wn + (fn << 4) + row16) * 32 + kg];
#pragma unroll
        for (int fm = 0; fm < 4; ++fm)
#pragma unroll
            for (int fn = 0; fn < 4; ++fn)
                acc[fm][fn] = __builtin_amdgcn_mfma_f32_16x16x32_bf16(
                    af[fm], bfv[fn], acc[fm][fn], 0, 0, 0);
        cur ^= 1;
    }

    float gate = (EPI == 1) ? *gatep : 0.f;
    int rbase = m0 + wm + ((lane >> 4) << 2);
#pragma unroll
    for (int fn = 0; fn < 4; ++fn) {
        int col = n0 + wn + (fn << 4) + (lane & 15);
        if (col >= N) continue;
        float bc = bias[col];
#pragma unroll
        for (int fm = 0; fm < 4; ++fm) {
#pragma unroll
            for (int r = 0; r < 4; ++r) {
                int row = rbase + (fm << 4) + r;
                float v = acc[fm][fn][r] + bc;
                if (EPI == 1)
                    v = resid[(size_t)row * N + col] + clampf(v, -100.f, 100.f) * gate;
                st1(&C[(size_t)row * N + col], v);
            }
        }
    }
}

// ---------------------------------------------------------------- depthwise causal conv (k=4) + SiLU, 8 ch/thread
// Per-batch causality via l = r & (L_SEQ-1); taps with lp<0 skipped exactly.
__global__ __launch_bounds__(192) void k_conv8(const bf16* __restrict__ x,
                                               const float* __restrict__ cw,
                                               const float* __restrict__ cb,
                                               bf16* __restrict__ xc) {
    int c0 = threadIdx.x * 8;          // 0..1528
    int r  = blockIdx.x;
    int l  = r & (L_SEQ - 1);
    float acc[8];
#pragma unroll
    for (int j = 0; j < 8; ++j) acc[j] = cb[c0 + j];
#pragma unroll
    for (int k = 0; k < 4; ++k) {
        int lp = l - 3 + k;
        if (lp < 0) continue;
        const short* px = (const short*)(x + (size_t)(r - 3 + k) * DINNER + c0);
        bf8v v = *(const bf8v*)px;
#pragma unroll
        for (int j = 0; j < 8; ++j)
            acc[j] += cw[(c0 + j) * 4 + k] * bs2f(v[j]);
    }
    bf8v o;
#pragma unroll
    for (int j = 0; j < 8; ++j) {
        float a = acc[j];
        o[j] = f2bs(a / (1.f + expf(-a)));
    }
    *(bf8v*)(xc + (size_t)r * DINNER + c0) = o;
}

// ---------------------------------------------------------------- per-(t,h): A value, 1/||B||, 1/||C||
__global__ __launch_bounds__(256) void k_prep(const bf16* __restrict__ xp,
                                              const float* __restrict__ A_log,
                                              float* __restrict__ Aarr,
                                              float* __restrict__ invB,
                                              float* __restrict__ invC) {
    int wv = threadIdx.x >> 6, lane = threadIdx.x & 63;
    int idx = blockIdx.x * 4 + wv;
    int t = idx / 24, h = idx - t * 24;
    const bf16* base = xp + (size_t)t * NPROJ + h * 129;
    float b = bf2f(base[1 + lane]), c = bf2f(base[65 + lane]);
    float sb = b * b, sc = c * c;
    for (int off = 32; off; off >>= 1) {
        sb += __shfl_xor(sb, off, 64);
        sc += __shfl_xor(sc, off, 64);
    }
    if (lane == 0) {
        invB[idx] = 1.f / fmaxf(sqrtf(sb), 1e-12f);
        invC[idx] = 1.f / fmaxf(sqrtf(sc), 1e-12f);
        float dt = clampf(bf2f(base[0]), -10.f, 10.f);
        float dts = clampf(log1pf(expf(dt)), 0.01f, 10.f);
        float A = clampf(A_log[h], -2.3f, -0.01f) * dts;
        Aarr[idx] = clampf(A, -20.f, -0.001f);
    }
}

// ---------------------------------------------------------------- chunk surprise via MFMA
__global__ __launch_bounds__(256) void k_surprise_all(const bf16* __restrict__ xp,
                                                      const bf16* __restrict__ xc,
                                                      const float* __restrict__ invB,
                                                      float* __restrict__ cs) {
    int g = blockIdx.x;                 // 0..6143
    int cg = g / 24, h = g - cg * 24;   // cg: global chunk 0..255
    int b = cg >> 7, nl = cg & 127;
    int t0 = cg * 64;
    size_t cs_idx = (size_t)(b * 24 + h) * 128 + nl;
    __shared__ short Ws[64 * 72];   // B^T : Ws[s][c]
    __shared__ short Xt[64 * 72];   // X^T : Xt[d][c]
    int tid = threadIdx.x, s = tid & 63, cg2 = tid >> 6;
    for (int it = 0; it < 16; ++it) {
        int c = cg2 + (it << 2);
        int t = t0 + c;
        Ws[s * 72 + c] = f2bs(bf2f(xp[(size_t)t * NPROJ + h * 129 + 1 + s]) * invB[t * 24 + h]);
        Xt[s * 72 + c] = *(const short*)&xc[(size_t)t * DINNER + h * 64 + s];
    }
    __syncthreads();
    int w = tid >> 6, lane = tid & 63;
    int r16 = lane & 15, kq = (lane >> 4) << 3;
    int strip = w << 4;
    f4v acc[4];
#pragma unroll
    for (int dt = 0; dt < 4; ++dt) acc[dt] = (f4v){0.f, 0.f, 0.f, 0.f};
#pragma unroll
    for (int ks = 0; ks < 2; ++ks) {
        bf8v af = *(const bf8v*)&Ws[(strip + r16) * 72 + ks * 32 + kq];
#pragma unroll
        for (int dt = 0; dt < 4; ++dt) {
            bf8v bf_ = *(const bf8v*)&Xt[((dt << 4) + r16) * 72 + ks * 32 + kq];
            acc[dt] = __builtin_amdgcn_mfma_f32_16x16x32_bf16(af, bf_, acc[dt], 0, 0, 0);
        }
    }
    float ss = 0.f;
#pragma unroll
    for (int dt = 0; dt < 4; ++dt)
#pragma unroll
        for (int r = 0; r < 4; ++r) ss += acc[dt][r] * acc[dt][r];
    for (int off = 32; off; off >>= 1) ss += __shfl_xor(ss, off, 64);
    __shared__ float ws4[4];
    if (lane == 0) ws4[w] = ss;
    __syncthreads();
    if (tid == 0) cs[cs_idx] = (ws4[0] + ws4[1] + ws4[2] + ws4[3]) * (1.f / 4096.f);
}

// ---------------------------------------------------------------- per-head EMA + alpha
__global__ __launch_bounds__(256) void k_alpha(const float* __restrict__ cs,
                                               const float* __restrict__ ema0,
                                               const float* __restrict__ l2ab,
                                               const float* __restrict__ l2b,
                                               float* __restrict__ alpha) {
    int h = blockIdx.x, tid = threadIdx.x;
    int b = tid >> 7, n = tid & 127;
    int gi = (b * 24 + h) * 128 + n;
    float v = cs[gi];
    float s = v;
    for (int off = 32; off; off >>= 1) s += __shfl_xor(s, off, 64);
    __shared__ float ws4[4];
    int lane = tid & 63, wv = tid >> 6;
    if (lane == 0) ws4[wv] = s;
    __syncthreads();
    float total = ws4[0] + ws4[1] + ws4[2] + ws4[3];
    float ema = 0.99f * ema0[h] + 0.01f * (total * (1.f / 256.f));
    float ab = 1.f - exp2f(clampf(l2ab[h], -3.32f, -0.015f));
    float beta = exp2f(clampf(l2b[h], -2.f, 2.f));
    float nz = v / (ema + 1e-6f);
    float boost = fmaxf(tanhf(beta * nz), 0.f);
    alpha[gi] = clampf(ab + (1.f - ab) * boost, 0.01f, 0.999f);
}

// ---------------------------------------------------------------- fused intra + hchunk via MFMA (shared body)
__device__ __forceinline__ void chunk_body(const bf16* xp, const bf16* xc,
                                           const float* invB, const float* invC,
                                           const float* Aarr, const float* alpha,
                                           bf16* ybuf, bf16* hf, float* dchunk,
                                           int t0, int h, size_t gidx, size_t hbase) {
    float alp = alpha[gidx];
    __shared__ short Cs[64 * 72];   // C rows [i][s]; later M [i][j]
    __shared__ short Bs[64 * 72];   // B rows [j][s]
    __shared__ short Ws[64 * 72];   // (dte·B)^T [s][c]
    __shared__ short Xt[64 * 72];   // X^T [d][c]
    __shared__ float Acs[64];
    __shared__ float dte[64];
    int tid = threadIdx.x;
    if (tid < 64) {
        float a = Aarr[(size_t)(t0 + tid) * 24 + h] * (1.f - alp);
        for (int off = 1; off < 64; off <<= 1) {
            float u = __shfl_up(a, off, 64);
            if (tid >= off) a += u;
        }
        Acs[tid] = a;
        float total = __shfl(a, 63, 64);
        dte[tid] = expf(total - a);
        if (tid == 0) dchunk[gidx] = expf(total);
    }
    __syncthreads();
    int s = tid & 63, cg = tid >> 6;
    for (int it = 0; it < 16; ++it) {
        int c = cg + (it << 2);
        int t = t0 + c;
        const bf16* bp = xp + (size_t)t * NPROJ + h * 129;
        float bv = bf2f(bp[1 + s]) * invB[t * 24 + h];
        Bs[c * 72 + s] = f2bs(bv);
        Ws[s * 72 + c] = f2bs(bv * dte[c]);
        Cs[c * 72 + s] = f2bs(bf2f(bp[65 + s]) * invC[t * 24 + h]);
        Xt[s * 72 + c] = *(const short*)&xc[(size_t)t * DINNER + h * 64 + s];
    }
    __syncthreads();
    int w = tid >> 6, lane = tid & 63;
    int r16 = lane & 15, kq = (lane >> 4) << 3;
    int strip = w << 4;
    f4v acb[4], ach[4];
#pragma unroll
    for (int jt = 0; jt < 4; ++jt) {
        acb[jt] = (f4v){0.f, 0.f, 0.f, 0.f};
        ach[jt] = (f4v){0.f, 0.f, 0.f, 0.f};
    }
#pragma unroll
    for (int ks = 0; ks < 2; ++ks) {
        bf8v afc = *(const bf8v*)&Cs[(strip + r16) * 72 + ks * 32 + kq];
        bf8v afw = *(const bf8v*)&Ws[(strip + r16) * 72 + ks * 32 + kq];
#pragma unroll
        for (int jt = 0; jt < 4; ++jt) {
            bf8v bb = *(const bf8v*)&Bs[((jt << 4) + r16) * 72 + ks * 32 + kq];
            acb[jt] = __builtin_amdgcn_mfma_f32_16x16x32_bf16(afc, bb, acb[jt], 0, 0, 0);
            bf8v xx = *(const bf8v*)&Xt[((jt << 4) + r16) * 72 + ks * 32 + kq];
            ach[jt] = __builtin_amdgcn_mfma_f32_16x16x32_bf16(afw, xx, ach[jt], 0, 0, 0);
        }
    }
    int rbase = strip + ((lane >> 4) << 2);
#pragma unroll
    for (int dt = 0; dt < 4; ++dt) {
        int d = (dt << 4) + r16;
#pragma unroll
        for (int r = 0; r < 4; ++r)
            hf[hbase + (size_t)(rbase + r) * 64 + d] = f2bf(ach[dt][r]);
    }
    __syncthreads();
    short* Ms = Cs;
#pragma unroll
    for (int jt = 0; jt < 4; ++jt) {
        int j = (jt << 4) + r16;
        float aj = Acs[j];
#pragma unroll
        for (int r = 0; r < 4; ++r) {
            int i = rbase + r;
            float m = (j <= i) ? expf(Acs[i] - aj) * acb[jt][r] : 0.f;
            Ms[i * 72 + j] = f2bs(m);
        }
    }
    __syncthreads();
    f4v acy[4];
#pragma unroll
    for (int dt = 0; dt < 4; ++dt) acy[dt] = (f4v){0.f, 0.f, 0.f, 0.f};
#pragma unroll
    for (int ks = 0; ks < 2; ++ks) {
        bf8v afm = *(const bf8v*)&Ms[(strip + r16) * 72 + ks * 32 + kq];
#pragma unroll
        for (int dt = 0; dt < 4; ++dt) {
            bf8v xx = *(const bf8v*)&Xt[((dt << 4) + r16) * 72 + ks * 32 + kq];
            acy[dt] = __builtin_amdgcn_mfma_f32_16x16x32_bf16(afm, xx, acy[dt], 0, 0, 0);
        }
    }
#pragma unroll
    for (int dt = 0; dt < 4; ++dt) {
        int d = (dt << 4) + r16;
#pragma unroll
        for (int r = 0; r < 4; ++r) {
            int i = rbase + r;
            ybuf[(size_t)(t0 + i) * DINNER + h * 64 + d] = f2bf(acy[dt][r]);
        }
    }
}

// segment-mode wrapper (BATCH fallback): arrays pre-offset per segment
__global__ __launch_bounds__(256) void k_chunk(const bf16* __restrict__ xp,
                                               const bf16* __restrict__ xc,
                                               const float* __restrict__ invB,
                                               const float* __restrict__ invC,
                                               const float* __restrict__ Aarr,
                                               const float* __restrict__ alpha,
                                               bf16* __restrict__ ybuf,
                                               bf16* __restrict__ hf,
                                               float* __restrict__ dchunk,
                                               int b, int l0, int lognch) {
    int g = blockIdx.x;
    int h = g >> lognch, nl = g & ((1 << lognch) - 1);
    chunk_body(xp, xc, invB, invC, Aarr, alpha, ybuf, hf, dchunk,
               nl * 64, h,
               (size_t)(b * 24 + h) * 128 + (l0 >> 6) + nl,
               (size_t)((h << lognch) + nl) * 4096);
}

// full-mode wrapper: grid 48*128, arrays full-NTOK
__global__ __launch_bounds__(256) void k_chunk_all(const bf16* __restrict__ xp,
                                                   const bf16* __restrict__ xc,
                                                   const float* __restrict__ invB,
                                                   const float* __restrict__ invC,
                                                   const float* __restrict__ Aarr,
                                                   const float* __restrict__ alpha,
                                                   bf16* __restrict__ ybuf,
                                                   bf16* __restrict__ hf,
                                                   float* __restrict__ dchunk) {
    int g = blockIdx.x;
    int bh = g >> 7, nl = g & 127;
    int b = bh >= 24 ? 1 : 0, h = bh - b * 24;
    size_t gidx = (size_t)bh * 128 + nl;
    chunk_body(xp, xc, invB, invC, Aarr, alpha, ybuf, hf, dchunk,
               b * L_SEQ + nl * 64, h, gidx, gidx * 4096);
}

// ---------------------------------------------------------------- chunk scan (prefetched)
__global__ __launch_bounds__(256) void k_scan(bf16* __restrict__ hf,
                                              const float* __restrict__ dchunk,
                                              float* __restrict__ carry,
                                              int b, int l0, int nch) {
    int h = blockIdx.x >> 4;
    int e = ((blockIdx.x & 15) << 8) + threadIdx.x;
    int bh = b * 24 + h;
    float c = (l0 == 0) ? 0.f : carry[(size_t)bh * 4096 + e];
    size_t a = (size_t)h * nch * 4096 + e;
    float v = bf2f(hf[a]);
    const float* dcp = dchunk + (size_t)bh * 128 + (l0 >> 6);
    for (int nl = 0; nl < nch; ++nl) {
        float dc = dcp[nl];
        float vn = (nl + 1 < nch) ? bf2f(hf[a + 4096]) : 0.f;
        hf[a] = f2bf(c);
        c = dc * c + v;
        v = vn;
        a += 4096;
    }
    carry[(size_t)bh * 4096 + e] = c;
}

// full-mode scan: grid 48*16, both batches, carry-free
__global__ __launch_bounds__(256) void k_scan_all(bf16* __restrict__ hf,
                                                  const float* __restrict__ dchunk) {
    int bh = blockIdx.x >> 4;
    int e = ((blockIdx.x & 15) << 8) + threadIdx.x;
    float c = 0.f;
    size_t a = (size_t)bh * 128 * 4096 + e;
    float v = bf2f(hf[a]);
    const float* dcp = dchunk + (size_t)bh * 128;
    for (int nl = 0; nl < 128; ++nl) {
        float dc = dcp[nl];
        float vn = (nl + 1 < 128) ? bf2f(hf[a + 4096]) : 0.f;
        hf[a] = f2bf(c);
        c = dc * c + v;
        v = vn;
        a += 4096;
    }
}

// ---------------------------------------------------------------- Y_inter + gate via MFMA (shared body)
__device__ __forceinline__ void inter_body(const bf16* xp, const float* invC,
                                           const float* Aarr, const float* alpha,
                                           const bf16* hf, const bf16* zbuf,
                                           bf16* ybuf,
                                           int t0, int h, size_t gidx, size_t hbase) {
    float alp = alpha[gidx];
    __shared__ short Cs[64 * 72];
    __shared__ short Ht[64 * 72];
    __shared__ float dfs[64];
    int tid = threadIdx.x;
    if (tid < 64) {
        float a = Aarr[(size_t)(t0 + tid) * 24 + h] * (1.f - alp);
        for (int off = 1; off < 64; off <<= 1) {
            float u = __shfl_up(a, off, 64);
            if (tid >= off) a += u;
        }
        dfs[tid] = expf(a);
    }
    int s = tid & 63, cg = tid >> 6;
    for (int it = 0; it < 16; ++it) {
        int c = cg + (it << 2);
        int t = t0 + c;
        Cs[c * 72 + s] = f2bs(bf2f(xp[(size_t)t * NPROJ + h * 129 + 65 + s]) * invC[t * 24 + h]);
        Ht[s * 72 + c] = *(const short*)&hf[hbase + (size_t)c * 64 + s];
    }
    __syncthreads();
    int w = tid >> 6, lane = tid & 63;
    int r16 = lane & 15, kq = (lane >> 4) << 3;
    int strip = w << 4;
    f4v acc[4];
#pragma unroll
    for (int dt = 0; dt < 4; ++dt) acc[dt] = (f4v){0.f, 0.f, 0.f, 0.f};
#pragma unroll
    for (int ks = 0; ks < 2; ++ks) {
        bf8v af = *(const bf8v*)&Cs[(strip + r16) * 72 + ks * 32 + kq];
#pragma unroll
        for (int dt = 0; dt < 4; ++dt) {
            bf8v hfr = *(const bf8v*)&Ht[((dt << 4) + r16) * 72 + ks * 32 + kq];
            acc[dt] = __builtin_amdgcn_mfma_f32_16x16x32_bf16(af, hfr, acc[dt], 0, 0, 0);
        }
    }
    int ibase = strip + ((lane >> 4) << 2);
#pragma unroll
    for (int dt = 0; dt < 4; ++dt) {
        int d = (dt << 4) + r16;
#pragma unroll
        for (int r = 0; r < 4; ++r) {
            int i = ibase + r;
            float df = dfs[i];
            size_t yoff = (size_t)(t0 + i) * DINNER + h * 64 + d;
            float Y = clampf(bf2f(ybuf[yoff]) + df * acc[dt][r], -100.f, 100.f);
            float zz = bf2f(zbuf[yoff]);
            ybuf[yoff] = f2bf(Y / (1.f + expf(-zz)));
        }
    }
}

__global__ __launch_bounds__(256) void k_inter(const bf16* __restrict__ xp,
                                               const float* __restrict__ invC,
                                               const float* __restrict__ Aarr,
                                               const float* __restrict__ alpha,
                                               const bf16* __restrict__ hf,
                                               const bf16* __restrict__ zbuf,
                                               bf16* __restrict__ ybuf,
                                               int b, int l0, int lognch) {
    int g = blockIdx.x;
    int h = g >> lognch, nl = g & ((1 << lognch) - 1);
    inter_body(xp, invC, Aarr, alpha, hf, zbuf, ybuf,
               nl * 64, h,
               (size_t)(b * 24 + h) * 128 + (l0 >> 6) + nl,
               (size_t)((h << lognch) + nl) * 4096);
}

__global__ __launch_bounds__(256) void k_inter_all(const bf16* __restrict__ xp,
                                                   const float* __restrict__ invC,
                                                   const float* __restrict__ Aarr,
                                                   const float* __restrict__ alpha,
                                                   const bf16* __restrict__ hf,
                                                   const bf16* __restrict__ zbuf,
                                                   bf16* __restrict__ ybuf) {
    int g = blockIdx.x;
    int bh = g >> 7, nl = g & 127;
    int b = bh >= 24 ? 1 : 0, h = bh - b * 24;
    size_t gidx = (size_t)bh * 128 + nl;
    inter_body(xp, invC, Aarr, alpha, hf, zbuf, ybuf,
               b * L_SEQ + nl * 64, h, gidx, gidx * 4096);
}

// ---------------------------------------------------------------- launch
extern "C" void kernel_launch(void* const* d_in, const int* in_sizes, int n_in,
                              void* d_out, int out_size, void* d_ws, size_t ws_size,
                              hipStream_t stream) {
    const float* hs     = (const float*)d_in[0];
    const float* norm_w = (const float*)d_in[1];
    const float* w1     = (const float*)d_in[2];
    const float* b1     = (const float*)d_in[3];
    const float* cw     = (const float*)d_in[4];
    const float* cbias  = (const float*)d_in[5];
    const float* w2     = (const float*)d_in[6];
    const float* b2     = (const float*)d_in[7];
    const float* A_log  = (const float*)d_in[8];
    const float* l2ab   = (const float*)d_in[9];
    const float* l2b    = (const float*)d_in[10];
    const float* ema0   = (const float*)d_in[11];
    const float* w3     = (const float*)d_in[12];
    const float* b3     = (const float*)d_in[13];
    const float* rg     = (const float*)d_in[14];
    float* out = (float*)d_out;

    // FULL: everything at NTOK granularity (~250 MB). BATCH (proven, R10): per-batch phase 2.
    const bool FULL  = ws_size >= (size_t)252 * 1000 * 1000;
    const int  SEG   = FULL ? NTOK : 8192;    // rows in ybuf/hf allocations

    char* base = (char*)d_ws;
    size_t off = 0;
    auto alloc = [&](size_t bytes) -> void* {
        void* p = base + off;
        off += (bytes + 255) & ~(size_t)255;
        return p;
    };
    bf16* w1bf  = (bf16*)alloc((size_t)2 * DINNER * DMODEL * 2);
    bf16* w2bf  = (bf16*)alloc((size_t)NPROJP * DINNER * 2);
    bf16* w3bf  = (bf16*)alloc((size_t)DMODEL * DINNER * 2);
    bf16* xn    = (bf16*)alloc((size_t)NTOK * DMODEL * 2);
    bf16* ybuf  = (bf16*)alloc((size_t)SEG * DINNER * 2);
    bf16* hf    = (bf16*)alloc((size_t)SEG / 64 * NHEADS * 4096 * 2);
    float* cs   = (float*)alloc((size_t)6144 * 4);
    float* alp  = (float*)alloc((size_t)6144 * 4);
    float* dch  = (float*)alloc((size_t)6144 * 4);
    float* carry= (float*)alloc((size_t)48 * 4096 * 4);
    bf16* xp    = (bf16*)alloc((size_t)NTOK * NPROJ * 2);
    float* Aarr = (float*)alloc((size_t)NTOK * 24 * 4);
    float* invB = (float*)alloc((size_t)NTOK * 24 * 4);
    float* invC = (float*)alloc((size_t)NTOK * 24 * 4);
    bf16* xbuf  = ybuf;                    // pre-conv x aliases ybuf
    bf16* xc_all = (bf16*)d_out;           // xc for all tokens lives in d_out

    {
        int n1 = 2 * DINNER * DMODEL / 4, n2 = NPROJ * DINNER / 4, n3 = DMODEL * DINNER / 4;
        k_cvt<<<(n1 + 255) / 256, 256, 0, stream>>>(w1, w1bf, n1);
        k_cvt<<<(n2 + 255) / 256, 256, 0, stream>>>(w2, w2bf, n2);
        k_cvt<<<(n3 + 255) / 256, 256, 0, stream>>>(w3, w3bf, n3);
        int nz = (NPROJP - NPROJ) * DINNER;
        k_zero<<<(nz + 255) / 256, 256, 0, stream>>>(w2bf + (size_t)NPROJ * DINNER, nz);
    }

    const dim3 gPall(NPROJP / 128, NTOK / 128);          // 25 x 128

    if (FULL) {
        // ============ full-sequence path: every op once over 16384 tokens
        const dim3 gX16(DINNER / 128, NTOK / 128);       // 12 x 128
        const dim3 gO16(DMODEL / 128, NTOK / 128);       // 6 x 128
        k_rmsnorm<<<NTOK, 256, 0, stream>>>(hs, norm_w, xn);
        k_mgemm<bf16, 0><<<gX16, 256, 0, stream>>>(xn, w1bf, b1, xbuf,
                                                   NTOK, DINNER, DMODEL, nullptr, nullptr);
        k_conv8<<<NTOK, 192, 0, stream>>>(xbuf, cw, cbias, xc_all);
        k_mgemm<bf16, 0><<<gPall, 256, 0, stream>>>(xc_all, w2bf, b2, xp,
                                                    NTOK, NPROJ, DINNER, nullptr, nullptr);
        k_prep<<<NTOK * 24 / 4, 256, 0, stream>>>(xp, A_log, Aarr, invB, invC);
        k_surprise_all<<<6144, 256, 0, stream>>>(xp, xc_all, invB, cs);
        k_alpha<<<24, 256, 0, stream>>>(cs, ema0, l2ab, l2b, alp);

        k_chunk_all<<<6144, 256, 0, stream>>>(xp, xc_all, invB, invC, Aarr, alp,
                                              ybuf, hf, dch);
        // z overwrites dead xc region (all of d_out)
        k_mgemm<bf16, 0><<<gX16, 256, 0, stream>>>(xn, w1bf + (size_t)DINNER * DMODEL,
                                                   b1 + DINNER, xc_all,
                                                   NTOK, DINNER, DMODEL, nullptr, nullptr);
        k_scan_all<<<768, 256, 0, stream>>>(hf, dch);
        k_inter_all<<<6144, 256, 0, stream>>>(xp, invC, Aarr, alp, hf, xc_all, ybuf);
        k_mgemm<float, 1><<<gO16, 256, 0, stream>>>(ybuf, w3bf, b3, out,
                                                    NTOK, DMODEL, DINNER, hs, rg);
        return;
    }

    // ============ BATCH fallback (proven R10 structure, conv8 instead of conv)
    const dim3 gXb(DINNER / 128, 8192 / 128);            // 12 x 64
    const dim3 gOb(DMODEL / 128, 8192 / 128);            // 6 x 64
    k_rmsnorm<<<NTOK, 256, 0, stream>>>(hs, norm_w, xn);
    for (int bt = 0; bt < 2; ++bt) {
        size_t t0 = (size_t)bt * 8192;
        k_mgemm<bf16, 0><<<gXb, 256, 0, stream>>>(xn + t0 * DMODEL, w1bf, b1, xbuf,
                                                  8192, DINNER, DMODEL, nullptr, nullptr);
        k_conv8<<<8192, 192, 0, stream>>>(xbuf, cw, cbias, xc_all + t0 * DINNER);
    }
    k_mgemm<bf16, 0><<<gPall, 256, 0, stream>>>(xc_all, w2bf, b2, xp,
                                                NTOK, NPROJ, DINNER, nullptr, nullptr);
    k_prep<<<NTOK * 24 / 4, 256, 0, stream>>>(xp, A_log, Aarr, invB, invC);
    k_surprise_all<<<6144, 256, 0, stream>>>(xp, xc_all, invB, cs);
    k_alpha<<<24, 256, 0, stream>>>(cs, ema0, l2ab, l2b, alp);

    for (int bt = 0; bt < 2; ++bt) {
        size_t t0 = (size_t)bt * 8192;
        bf16* xc = xc_all + t0 * DINNER;
        bf16* zseg = xc;
        const bf16* xpS = xp + t0 * NPROJ;
        const float* AarrS = Aarr + t0 * 24;
        const float* invBS = invB + t0 * 24;
        const float* invCS = invC + t0 * 24;
        k_chunk<<<NHEADS * 128, 256, 0, stream>>>(xpS, xc, invBS, invCS, AarrS, alp,
                                                  ybuf, hf, dch, bt, 0, 7);
        k_mgemm<bf16, 0><<<gXb, 256, 0, stream>>>(xn + t0 * DMODEL,
                                                  w1bf + (size_t)DINNER * DMODEL,
                                                  b1 + DINNER, zseg,
                                                  8192, DINNER, DMODEL, nullptr, nullptr);
        k_scan<<<384, 256, 0, stream>>>(hf, dch, carry, bt, 0, 128);
        k_inter<<<NHEADS * 128, 256, 0, stream>>>(xpS, invCS, AarrS, alp, hf, zseg,
                                                  ybuf, bt, 0, 7);
        k_mgemm<float, 1><<<gOb, 256, 0, stream>>>(ybuf, w3bf, b3, out + t0 * DMODEL,
                                                   8192, DMODEL, DINNER,
                                                   hs + t0 * DMODEL, rg);
    }
}

// Round 12
// 907.431 us; speedup vs baseline: 1.0789x; 1.0789x over previous
//
#include <hip/hip_runtime.h>
#include <hip/hip_bf16.h>
#include <cstdint>
#include <cstddef>

#define L_SEQ   8192
#define DMODEL  768
#define NHEADS  24
#define DINNER  1536
#define NPROJ   3096      /* logical proj cols: 24 * 129 */
#define NPROJP  3200      /* padded weight rows for gload_lds */
#define NPROJ2  3264      /* padded xp row stride: 24 * 136 */
#define HSTR    136       /* per-head stride in padded xp: dt@0, B@8, C@72 */
#define NTOK    16384
#define SEG_T   4096
#define NSEG    4
#define RMS_EPS 1.1920929e-07f

typedef __hip_bfloat16 bf16;
typedef __attribute__((ext_vector_type(8))) short bf8v;
typedef __attribute__((ext_vector_type(4))) float f4v;

__device__ __forceinline__ float clampf(float x, float lo, float hi) {
    return fminf(fmaxf(x, lo), hi);
}
__device__ __forceinline__ float bf2f(bf16 v) { return __bfloat162float(v); }
__device__ __forceinline__ bf16  f2bf(float v) { return __float2bfloat16(v); }
__device__ __forceinline__ short f2bs(float v) {
    bf16 b = __float2bfloat16(v);
    return *reinterpret_cast<short*>(&b);
}
__device__ __forceinline__ float bs2f(short v) {
    return __uint_as_float(((unsigned)(unsigned short)v) << 16);
}
__device__ __forceinline__ void st1(float* p, float v) { *p = v; }
__device__ __forceinline__ void st1(bf16* p, float v) { *p = f2bf(v); }
__device__ __forceinline__ void st4(bf16* p, float4 v) {
    p[0] = f2bf(v.x); p[1] = f2bf(v.y); p[2] = f2bf(v.z); p[3] = f2bf(v.w);
}

#define GLOAD16(gsrc, ldst) __builtin_amdgcn_global_load_lds( \
    (const __attribute__((address_space(1))) void*)(gsrc),    \
    (__attribute__((address_space(3))) void*)(ldst), 16, 0, 0)

// ---------------------------------------------------------------- weight cvt / zero
__global__ __launch_bounds__(256) void k_cvt(const float* __restrict__ s,
                                             bf16* __restrict__ d, int n4) {
    int i = blockIdx.x * 256 + threadIdx.x;
    if (i < n4) {
        float4 v = *(const float4*)&s[i * 4];
        st4(&d[i * 4], v);
    }
}
__global__ __launch_bounds__(256) void k_zero(bf16* __restrict__ d, int n) {
    int i = blockIdx.x * 256 + threadIdx.x;
    if (i < n) d[i] = f2bf(0.f);
}

// ---------------------------------------------------------------- RMSNorm
__global__ __launch_bounds__(256) void k_rmsnorm(const float* __restrict__ hs,
                                                 const float* __restrict__ w,
                                                 bf16* __restrict__ xn) {
    int t = blockIdx.x;
    const float* p = hs + (size_t)t * DMODEL;
    float s = 0.f;
    for (int i = threadIdx.x; i < DMODEL; i += 256) { float v = p[i]; s += v * v; }
    for (int off = 32; off; off >>= 1) s += __shfl_xor(s, off, 64);
    __shared__ float ws4[4];
    int lane = threadIdx.x & 63, wv = threadIdx.x >> 6;
    if (lane == 0) ws4[wv] = s;
    __syncthreads();
    s = ws4[0] + ws4[1] + ws4[2] + ws4[3];
    float r = 1.0f / sqrtf(s * (1.0f / DMODEL) + RMS_EPS);
    bf16* o = xn + (size_t)t * DMODEL;
    for (int i = threadIdx.x; i < DMODEL; i += 256) o[i] = f2bf(p[i] * r * w[i]);
}

// ---------------------------------------------------------------- MFMA GEMM
// EPI 0: C[row*N+col] = acc+bias   EPI 1: +resid/clip/gate (f32)
// EPI 2: padded-xp store: C[row*NPROJ2 + h*136 + (q?q+7:0)], h=col/129
template <typename TC, int EPI>
__global__ __launch_bounds__(256) void k_mgemm(const bf16* __restrict__ A,
                                               const bf16* __restrict__ B,
                                               const float* __restrict__ bias,
                                               TC* __restrict__ C,
                                               int M, int N, int K,
                                               const float* __restrict__ resid,
                                               const float* __restrict__ gatep) {
    __shared__ short As[2][128 * 32];
    __shared__ short Bs[2][128 * 32];
    int tid = threadIdx.x;
    int lane = tid & 63, w = tid >> 6;

    int gx = gridDim.x, gy = gridDim.y;
    int bid = blockIdx.y * gx + blockIdx.x;
    int xcd = bid & 7, idx = bid >> 3;
    int bys = gy >> 3;
    int gby = bys < 8 ? bys : 8;
    int sg  = idx / (gx * gby);
    int rem = idx - sg * (gx * gby);
    int bx  = rem / gby;
    int byl = rem - bx * gby;
    int by  = xcd * bys + sg * gby + byl;
    int m0 = by * 128, n0 = bx * 128;

    int wm = (w >> 1) << 6, wn = (w & 1) << 6;

    const size_t rowskip = (size_t)16 * K * 2;
    const char* Ag = (const char*)(A + (size_t)(m0 + (w << 5) + (lane >> 2)) * K) + (lane & 3) * 16;
    const char* Bg = (const char*)(B + (size_t)(n0 + (w << 5) + (lane >> 2)) * K) + (lane & 3) * 16;
    short* Al0 = &As[0][(w << 5) * 32];
    short* Bl0 = &Bs[0][(w << 5) * 32];
    short* Al1 = &As[1][(w << 5) * 32];
    short* Bl1 = &Bs[1][(w << 5) * 32];

    f4v acc[4][4];
#pragma unroll
    for (int i = 0; i < 4; ++i)
#pragma unroll
        for (int j = 0; j < 4; ++j) acc[i][j] = (f4v){0.f, 0.f, 0.f, 0.f};

    auto stage = [&](int buf, int k0) {
        size_t kb = (size_t)k0 * 2;
        short* Al = buf ? Al1 : Al0;
        short* Bl = buf ? Bl1 : Bl0;
        GLOAD16(Ag + kb,           Al);
        GLOAD16(Ag + kb + rowskip, Al + 16 * 32);
        GLOAD16(Bg + kb,           Bl);
        GLOAD16(Bg + kb + rowskip, Bl + 16 * 32);
    };

    stage(0, 0);
    int cur = 0;
    int row16 = lane & 15, kg = (lane >> 4) << 3;
    for (int k0 = 0; k0 < K; k0 += 32) {
        __syncthreads();
        if (k0 + 32 < K) stage(cur ^ 1, k0 + 32);
        const short* Ab = As[cur];
        const short* Bb = Bs[cur];
        bf8v af[4], bfv[4];
#pragma unroll
        for (int fm = 0; fm < 4; ++fm)
            af[fm] = *(const bf8v*)&Ab[(wm + (fm << 4) + row16) * 32 + kg];
#pragma unroll
        for (int fn = 0; fn < 4; ++fn)
            bfv[fn] = *(const bf8v*)&Bb[(wn + (fn << 4) + row16) * 32 + kg];
#pragma unroll
        for (int fm = 0; fm < 4; ++fm)
#pragma unroll
            for (int fn = 0; fn < 4; ++fn)
                acc[fm][fn] = __builtin_amdgcn_mfma_f32_16x16x32_bf16(
                    af[fm], bfv[fn], acc[fm][fn], 0, 0, 0);
        cur ^= 1;
    }

    float gate = (EPI == 1) ? *gatep : 0.f;
    int rbase = m0 + wm + ((lane >> 4) << 2);
#pragma unroll
    for (int fn = 0; fn < 4; ++fn) {
        int col = n0 + wn + (fn << 4) + (lane & 15);
        if (col >= N) continue;
        float bc = bias[col];
        int dst = col;
        if (EPI == 2) {
            int hh = col / 129, q = col - hh * 129;
            dst = hh * HSTR + (q == 0 ? 0 : q + 7);
        }
#pragma unroll
        for (int fm = 0; fm < 4; ++fm) {
#pragma unroll
            for (int r = 0; r < 4; ++r) {
                int row = rbase + (fm << 4) + r;
                float v = acc[fm][fn][r] + bc;
                if (EPI == 1) {
                    v = resid[(size_t)row * N + col] + clampf(v, -100.f, 100.f) * gate;
                    st1(&C[(size_t)row * N + col], v);
                } else if (EPI == 2) {
                    st1(&C[(size_t)row * NPROJ2 + dst], v);
                } else {
                    st1(&C[(size_t)row * N + col], v);
                }
            }
        }
    }
}

// ---------------------------------------------------------------- save last 3 rows (segment conv halo)
__global__ __launch_bounds__(256) void k_save_halo(const bf16* __restrict__ x,
                                                   bf16* __restrict__ dst) {
    int i = blockIdx.x * 256 + threadIdx.x;
    if (i < 3 * DINNER) dst[i] = x[(size_t)(SEG_T - 3) * DINNER + i];
}

// ---------------------------------------------------------------- conv+SiLU, FULL mode (8 ch/thread)
__global__ __launch_bounds__(192) void k_conv8(const bf16* __restrict__ x,
                                               const float* __restrict__ cw,
                                               const float* __restrict__ cb,
                                               bf16* __restrict__ xc) {
    int c0 = threadIdx.x * 8;
    int r  = blockIdx.x;
    int l  = r & (L_SEQ - 1);
    float acc[8];
#pragma unroll
    for (int j = 0; j < 8; ++j) acc[j] = cb[c0 + j];
#pragma unroll
    for (int k = 0; k < 4; ++k) {
        int lp = l - 3 + k;
        if (lp < 0) continue;
        bf8v v = *(const bf8v*)(const void*)(x + (size_t)(r - 3 + k) * DINNER + c0);
#pragma unroll
        for (int j = 0; j < 8; ++j)
            acc[j] += cw[(c0 + j) * 4 + k] * bs2f(v[j]);
    }
    bf8v o;
#pragma unroll
    for (int j = 0; j < 8; ++j) {
        float a = acc[j];
        o[j] = f2bs(a / (1.f + expf(-a)));
    }
    *(bf8v*)(xc + (size_t)r * DINNER + c0) = o;
}

// ---------------------------------------------------------------- conv+SiLU, segment mode (halo)
__global__ __launch_bounds__(256) void k_conv_silu(const bf16* __restrict__ x,
                                                   const bf16* __restrict__ xh,
                                                   const float* __restrict__ cw,
                                                   const float* __restrict__ cb,
                                                   bf16* __restrict__ xc,
                                                   int l0) {
    int c = blockIdx.x * 256 + threadIdx.x;
    int r = blockIdx.y;
    int l = l0 + r;
    float acc = cb[c];
#pragma unroll
    for (int k = 0; k < 4; ++k) {
        int lp = l - 3 + k;
        if (lp < 0) continue;
        float v = (lp < l0) ? bf2f(xh[(size_t)(lp - l0 + 3) * DINNER + c])
                            : bf2f(x[(size_t)(lp - l0) * DINNER + c]);
        acc += cw[c * 4 + k] * v;
    }
    float sig = 1.f / (1.f + expf(-acc));
    xc[(size_t)r * DINNER + c] = f2bf(acc * sig);
}

// ---------------------------------------------------------------- per-(t,h) prep (padded xp)
__global__ __launch_bounds__(256) void k_prep(const bf16* __restrict__ xp,
                                              const float* __restrict__ A_log,
                                              float* __restrict__ Aarr,
                                              float* __restrict__ invB,
                                              float* __restrict__ invC) {
    int wv = threadIdx.x >> 6, lane = threadIdx.x & 63;
    int idx = blockIdx.x * 4 + wv;
    int t = idx / 24, h = idx - t * 24;
    const bf16* base = xp + (size_t)t * NPROJ2 + h * HSTR;
    float b = bf2f(base[8 + lane]), c = bf2f(base[72 + lane]);
    float sb = b * b, sc = c * c;
    for (int off = 32; off; off >>= 1) {
        sb += __shfl_xor(sb, off, 64);
        sc += __shfl_xor(sc, off, 64);
    }
    if (lane == 0) {
        invB[idx] = 1.f / fmaxf(sqrtf(sb), 1e-12f);
        invC[idx] = 1.f / fmaxf(sqrtf(sc), 1e-12f);
        float dt = clampf(bf2f(base[0]), -10.f, 10.f);
        float dts = clampf(log1pf(expf(dt)), 0.01f, 10.f);
        float A = clampf(A_log[h], -2.3f, -0.01f) * dts;
        Aarr[idx] = clampf(A, -20.f, -0.001f);
    }
}

// ---------------------------------------------------------------- surprise (vectorized staging)
__global__ __launch_bounds__(256) void k_surprise_all(const bf16* __restrict__ xp,
                                                      const bf16* __restrict__ xc,
                                                      const float* __restrict__ invB,
                                                      float* __restrict__ cs) {
    int g = blockIdx.x;                 // 0..6143
    int cg = g / 24, h = g - cg * 24;
    int b = cg >> 7, nl = cg & 127;
    int t0 = cg * 64;
    size_t cs_idx = (size_t)(b * 24 + h) * 128 + nl;
    __shared__ short Ws[64 * 72];   // B^T [s][c]
    __shared__ short Xt[64 * 72];   // X^T [d][c]
    int tid = threadIdx.x;
#pragma unroll
    for (int half = 0; half < 2; ++half) {
        int tau = tid + half * 256;
        int c = tau >> 3, s0 = (tau & 7) << 3;
        int t = t0 + c;
        float ib = invB[t * 24 + h];
        bf8v Bv = *(const bf8v*)(const void*)(xp + (size_t)t * NPROJ2 + h * HSTR + 8 + s0);
        bf8v Xv = *(const bf8v*)(const void*)(xc + (size_t)t * DINNER + h * 64 + s0);
#pragma unroll
        for (int u = 0; u < 8; ++u) {
            Ws[(s0 + u) * 72 + c] = f2bs(bs2f(Bv[u]) * ib);
            Xt[(s0 + u) * 72 + c] = Xv[u];
        }
    }
    __syncthreads();
    int w = tid >> 6, lane = tid & 63;
    int r16 = lane & 15, kq = (lane >> 4) << 3;
    int strip = w << 4;
    f4v acc[4];
#pragma unroll
    for (int dt = 0; dt < 4; ++dt) acc[dt] = (f4v){0.f, 0.f, 0.f, 0.f};
#pragma unroll
    for (int ks = 0; ks < 2; ++ks) {
        bf8v af = *(const bf8v*)&Ws[(strip + r16) * 72 + ks * 32 + kq];
#pragma unroll
        for (int dt = 0; dt < 4; ++dt) {
            bf8v bf_ = *(const bf8v*)&Xt[((dt << 4) + r16) * 72 + ks * 32 + kq];
            acc[dt] = __builtin_amdgcn_mfma_f32_16x16x32_bf16(af, bf_, acc[dt], 0, 0, 0);
        }
    }
    float ss = 0.f;
#pragma unroll
    for (int dt = 0; dt < 4; ++dt)
#pragma unroll
        for (int r = 0; r < 4; ++r) ss += acc[dt][r] * acc[dt][r];
    for (int off = 32; off; off >>= 1) ss += __shfl_xor(ss, off, 64);
    __shared__ float ws4[4];
    if (lane == 0) ws4[w] = ss;
    __syncthreads();
    if (tid == 0) cs[cs_idx] = (ws4[0] + ws4[1] + ws4[2] + ws4[3]) * (1.f / 4096.f);
}

// ---------------------------------------------------------------- per-head EMA + alpha
__global__ __launch_bounds__(256) void k_alpha(const float* __restrict__ cs,
                                               const float* __restrict__ ema0,
                                               const float* __restrict__ l2ab,
                                               const float* __restrict__ l2b,
                                               float* __restrict__ alpha) {
    int h = blockIdx.x, tid = threadIdx.x;
    int b = tid >> 7, n = tid & 127;
    int gi = (b * 24 + h) * 128 + n;
    float v = cs[gi];
    float s = v;
    for (int off = 32; off; off >>= 1) s += __shfl_xor(s, off, 64);
    __shared__ float ws4[4];
    int lane = tid & 63, wv = tid >> 6;
    if (lane == 0) ws4[wv] = s;
    __syncthreads();
    float total = ws4[0] + ws4[1] + ws4[2] + ws4[3];
    float ema = 0.99f * ema0[h] + 0.01f * (total * (1.f / 256.f));
    float ab = 1.f - exp2f(clampf(l2ab[h], -3.32f, -0.015f));
    float beta = exp2f(clampf(l2b[h], -2.f, 2.f));
    float nz = v / (ema + 1e-6f);
    float boost = fmaxf(tanhf(beta * nz), 0.f);
    alpha[gi] = clampf(ab + (1.f - ab) * boost, 0.01f, 0.999f);
}

// ---------------------------------------------------------------- fused intra+hchunk (vectorized staging)
__device__ __forceinline__ void chunk_body(const bf16* xp, const bf16* xc,
                                           const float* invB, const float* invC,
                                           const float* Aarr, const float* alpha,
                                           bf16* ybuf, bf16* hf, float* dchunk,
                                           int t0, int h, size_t gidx, size_t hbase) {
    float alp = alpha[gidx];
    __shared__ short Cs[64 * 72];   // C rows [i][s]; later M [i][j]
    __shared__ short Bs[64 * 72];   // B rows [j][s]
    __shared__ short Ws[64 * 72];   // (dte·B)^T [s][c]
    __shared__ short Xt[64 * 72];   // X^T [d][c]
    __shared__ float Acs[64];
    __shared__ float dte[64];
    int tid = threadIdx.x;
    if (tid < 64) {
        float a = Aarr[(size_t)(t0 + tid) * 24 + h] * (1.f - alp);
        for (int off = 1; off < 64; off <<= 1) {
            float u = __shfl_up(a, off, 64);
            if (tid >= off) a += u;
        }
        Acs[tid] = a;
        float total = __shfl(a, 63, 64);
        dte[tid] = expf(total - a);
        if (tid == 0) dchunk[gidx] = expf(total);
    }
    __syncthreads();                 // Acs, dte ready
#pragma unroll
    for (int half = 0; half < 2; ++half) {
        int tau = tid + half * 256;
        int c = tau >> 3, s0 = (tau & 7) << 3;
        int t = t0 + c;
        const bf16* bp = xp + (size_t)t * NPROJ2 + h * HSTR;
        float ib = invB[t * 24 + h], ic2 = invC[t * 24 + h];
        float dc = dte[c];
        bf8v Bv = *(const bf8v*)(const void*)(bp + 8 + s0);
        bf8v Cv = *(const bf8v*)(const void*)(bp + 72 + s0);
        bf8v Xv = *(const bf8v*)(const void*)(xc + (size_t)t * DINNER + h * 64 + s0);
        bf8v Bsc, Csc;
#pragma unroll
        for (int u = 0; u < 8; ++u) {
            float bv = bs2f(Bv[u]) * ib;
            Bsc[u] = f2bs(bv);
            Csc[u] = f2bs(bs2f(Cv[u]) * ic2);
            Ws[(s0 + u) * 72 + c] = f2bs(bv * dc);
            Xt[(s0 + u) * 72 + c] = Xv[u];
        }
        *(bf8v*)&Bs[c * 72 + s0] = Bsc;
        *(bf8v*)&Cs[c * 72 + s0] = Csc;
    }
    __syncthreads();
    int w = tid >> 6, lane = tid & 63;
    int r16 = lane & 15, kq = (lane >> 4) << 3;
    int strip = w << 4;
    f4v acb[4], ach[4];
#pragma unroll
    for (int jt = 0; jt < 4; ++jt) {
        acb[jt] = (f4v){0.f, 0.f, 0.f, 0.f};
        ach[jt] = (f4v){0.f, 0.f, 0.f, 0.f};
    }
#pragma unroll
    for (int ks = 0; ks < 2; ++ks) {
        bf8v afc = *(const bf8v*)&Cs[(strip + r16) * 72 + ks * 32 + kq];
        bf8v afw = *(const bf8v*)&Ws[(strip + r16) * 72 + ks * 32 + kq];
#pragma unroll
        for (int jt = 0; jt < 4; ++jt) {
            bf8v bb = *(const bf8v*)&Bs[((jt << 4) + r16) * 72 + ks * 32 + kq];
            acb[jt] = __builtin_amdgcn_mfma_f32_16x16x32_bf16(afc, bb, acb[jt], 0, 0, 0);
            bf8v xx = *(const bf8v*)&Xt[((jt << 4) + r16) * 72 + ks * 32 + kq];
            ach[jt] = __builtin_amdgcn_mfma_f32_16x16x32_bf16(afw, xx, ach[jt], 0, 0, 0);
        }
    }
    int rbase = strip + ((lane >> 4) << 2);
#pragma unroll
    for (int dt = 0; dt < 4; ++dt) {
        int d = (dt << 4) + r16;
#pragma unroll
        for (int r = 0; r < 4; ++r)
            hf[hbase + (size_t)(rbase + r) * 64 + d] = f2bf(ach[dt][r]);
    }
    __syncthreads();
    short* Ms = Cs;
#pragma unroll
    for (int jt = 0; jt < 4; ++jt) {
        int j = (jt << 4) + r16;
        float aj = Acs[j];
#pragma unroll
        for (int r = 0; r < 4; ++r) {
            int i = rbase + r;
            float m = (j <= i) ? expf(Acs[i] - aj) * acb[jt][r] : 0.f;
            Ms[i * 72 + j] = f2bs(m);
        }
    }
    __syncthreads();
    f4v acy[4];
#pragma unroll
    for (int dt = 0; dt < 4; ++dt) acy[dt] = (f4v){0.f, 0.f, 0.f, 0.f};
#pragma unroll
    for (int ks = 0; ks < 2; ++ks) {
        bf8v afm = *(const bf8v*)&Ms[(strip + r16) * 72 + ks * 32 + kq];
#pragma unroll
        for (int dt = 0; dt < 4; ++dt) {
            bf8v xx = *(const bf8v*)&Xt[((dt << 4) + r16) * 72 + ks * 32 + kq];
            acy[dt] = __builtin_amdgcn_mfma_f32_16x16x32_bf16(afm, xx, acy[dt], 0, 0, 0);
        }
    }
#pragma unroll
    for (int dt = 0; dt < 4; ++dt) {
        int d = (dt << 4) + r16;
#pragma unroll
        for (int r = 0; r < 4; ++r) {
            int i = rbase + r;
            ybuf[(size_t)(t0 + i) * DINNER + h * 64 + d] = f2bf(acy[dt][r]);
        }
    }
}

__global__ __launch_bounds__(256) void k_chunk(const bf16* __restrict__ xp,
                                               const bf16* __restrict__ xc,
                                               const float* __restrict__ invB,
                                               const float* __restrict__ invC,
                                               const float* __restrict__ Aarr,
                                               const float* __restrict__ alpha,
                                               bf16* __restrict__ ybuf,
                                               bf16* __restrict__ hf,
                                               float* __restrict__ dchunk,
                                               int b, int l0) {
    int g = blockIdx.x;
    int h = g >> 6, nl = g & 63;
    chunk_body(xp, xc, invB, invC, Aarr, alpha, ybuf, hf, dchunk,
               nl * 64, h,
               (size_t)(b * 24 + h) * 128 + (l0 >> 6) + nl,
               (size_t)((h << 6) + nl) * 4096);
}

__global__ __launch_bounds__(256) void k_chunk_all(const bf16* __restrict__ xp,
                                                   const bf16* __restrict__ xc,
                                                   const float* __restrict__ invB,
                                                   const float* __restrict__ invC,
                                                   const float* __restrict__ Aarr,
                                                   const float* __restrict__ alpha,
                                                   bf16* __restrict__ ybuf,
                                                   bf16* __restrict__ hf,
                                                   float* __restrict__ dchunk) {
    int g = blockIdx.x;
    int bh = g >> 7, nl = g & 127;
    int b = bh >= 24 ? 1 : 0, h = bh - b * 24;
    size_t gidx = (size_t)bh * 128 + nl;
    chunk_body(xp, xc, invB, invC, Aarr, alpha, ybuf, hf, dchunk,
               b * L_SEQ + nl * 64, h, gidx, gidx * 4096);
}

// ---------------------------------------------------------------- chunk scan
__global__ __launch_bounds__(256) void k_scan(bf16* __restrict__ hf,
                                              const float* __restrict__ dchunk,
                                              float* __restrict__ carry,
                                              int b, int l0, int nch) {
    int h = blockIdx.x >> 4;
    int e = ((blockIdx.x & 15) << 8) + threadIdx.x;
    int bh = b * 24 + h;
    float c = (l0 == 0) ? 0.f : carry[(size_t)bh * 4096 + e];
    size_t a = (size_t)h * nch * 4096 + e;
    float v = bf2f(hf[a]);
    const float* dcp = dchunk + (size_t)bh * 128 + (l0 >> 6);
    for (int nl = 0; nl < nch; ++nl) {
        float dc = dcp[nl];
        float vn = (nl + 1 < nch) ? bf2f(hf[a + 4096]) : 0.f;
        hf[a] = f2bf(c);
        c = dc * c + v;
        v = vn;
        a += 4096;
    }
    carry[(size_t)bh * 4096 + e] = c;
}

__global__ __launch_bounds__(256) void k_scan_all(bf16* __restrict__ hf,
                                                  const float* __restrict__ dchunk) {
    int bh = blockIdx.x >> 4;
    int e = ((blockIdx.x & 15) << 8) + threadIdx.x;
    float c = 0.f;
    size_t a = (size_t)bh * 128 * 4096 + e;
    float v = bf2f(hf[a]);
    const float* dcp = dchunk + (size_t)bh * 128;
    for (int nl = 0; nl < 128; ++nl) {
        float dc = dcp[nl];
        float vn = (nl + 1 < 128) ? bf2f(hf[a + 4096]) : 0.f;
        hf[a] = f2bf(c);
        c = dc * c + v;
        v = vn;
        a += 4096;
    }
}

// ---------------------------------------------------------------- Y_inter + gate (vectorized staging)
__device__ __forceinline__ void inter_body(const bf16* xp, const float* invC,
                                           const float* Aarr, const float* alpha,
                                           const bf16* hf, const bf16* zbuf,
                                           bf16* ybuf,
                                           int t0, int h, size_t gidx, size_t hbase) {
    float alp = alpha[gidx];
    __shared__ short Cs[64 * 72];
    __shared__ short Ht[64 * 72];
    __shared__ float dfs[64];
    int tid = threadIdx.x;
    if (tid < 64) {
        float a = Aarr[(size_t)(t0 + tid) * 24 + h] * (1.f - alp);
        for (int off = 1; off < 64; off <<= 1) {
            float u = __shfl_up(a, off, 64);
            if (tid >= off) a += u;
        }
        dfs[tid] = expf(a);
    }
#pragma unroll
    for (int half = 0; half < 2; ++half) {
        int tau = tid + half * 256;
        int c = tau >> 3, s0 = (tau & 7) << 3;
        int t = t0 + c;
        float ic2 = invC[t * 24 + h];
        bf8v Cv = *(const bf8v*)(const void*)(xp + (size_t)t * NPROJ2 + h * HSTR + 72 + s0);
        bf8v Hv = *(const bf8v*)(const void*)(hf + hbase + (size_t)c * 64 + s0);
        bf8v Csc;
#pragma unroll
        for (int u = 0; u < 8; ++u) {
            Csc[u] = f2bs(bs2f(Cv[u]) * ic2);
            Ht[(s0 + u) * 72 + c] = Hv[u];
        }
        *(bf8v*)&Cs[c * 72 + s0] = Csc;
    }
    __syncthreads();
    int w = tid >> 6, lane = tid & 63;
    int r16 = lane & 15, kq = (lane >> 4) << 3;
    int strip = w << 4;
    f4v acc[4];
#pragma unroll
    for (int dt = 0; dt < 4; ++dt) acc[dt] = (f4v){0.f, 0.f, 0.f, 0.f};
#pragma unroll
    for (int ks = 0; ks < 2; ++ks) {
        bf8v af = *(const bf8v*)&Cs[(strip + r16) * 72 + ks * 32 + kq];
#pragma unroll
        for (int dt = 0; dt < 4; ++dt) {
            bf8v hfr = *(const bf8v*)&Ht[((dt << 4) + r16) * 72 + ks * 32 + kq];
            acc[dt] = __builtin_amdgcn_mfma_f32_16x16x32_bf16(af, hfr, acc[dt], 0, 0, 0);
        }
    }
    int ibase = strip + ((lane >> 4) << 2);
#pragma unroll
    for (int dt = 0; dt < 4; ++dt) {
        int d = (dt << 4) + r16;
#pragma unroll
        for (int r = 0; r < 4; ++r) {
            int i = ibase + r;
            float df = dfs[i];
            size_t yoff = (size_t)(t0 + i) * DINNER + h * 64 + d;
            float Y = clampf(bf2f(ybuf[yoff]) + df * acc[dt][r], -100.f, 100.f);
            float zz = bf2f(zbuf[yoff]);
            ybuf[yoff] = f2bf(Y / (1.f + expf(-zz)));
        }
    }
}

__global__ __launch_bounds__(256) void k_inter(const bf16* __restrict__ xp,
                                               const float* __restrict__ invC,
                                               const float* __restrict__ Aarr,
                                               const float* __restrict__ alpha,
                                               const bf16* __restrict__ hf,
                                               const bf16* __restrict__ zbuf,
                                               bf16* __restrict__ ybuf,
                                               int b, int l0) {
    int g = blockIdx.x;
    int h = g >> 6, nl = g & 63;
    inter_body(xp, invC, Aarr, alpha, hf, zbuf, ybuf,
               nl * 64, h,
               (size_t)(b * 24 + h) * 128 + (l0 >> 6) + nl,
               (size_t)((h << 6) + nl) * 4096);
}

__global__ __launch_bounds__(256) void k_inter_all(const bf16* __restrict__ xp,
                                                   const float* __restrict__ invC,
                                                   const float* __restrict__ Aarr,
                                                   const float* __restrict__ alpha,
                                                   const bf16* __restrict__ hf,
                                                   const bf16* __restrict__ zbuf,
                                                   bf16* __restrict__ ybuf) {
    int g = blockIdx.x;
    int bh = g >> 7, nl = g & 127;
    int b = bh >= 24 ? 1 : 0, h = bh - b * 24;
    size_t gidx = (size_t)bh * 128 + nl;
    inter_body(xp, invC, Aarr, alpha, hf, zbuf, ybuf,
               b * L_SEQ + nl * 64, h, gidx, gidx * 4096);
}

// ---------------------------------------------------------------- launch
extern "C" void kernel_launch(void* const* d_in, const int* in_sizes, int n_in,
                              void* d_out, int out_size, void* d_ws, size_t ws_size,
                              hipStream_t stream) {
    const float* hs     = (const float*)d_in[0];
    const float* norm_w = (const float*)d_in[1];
    const float* w1     = (const float*)d_in[2];
    const float* b1     = (const float*)d_in[3];
    const float* cw     = (const float*)d_in[4];
    const float* cbias  = (const float*)d_in[5];
    const float* w2     = (const float*)d_in[6];
    const float* b2     = (const float*)d_in[7];
    const float* A_log  = (const float*)d_in[8];
    const float* l2ab   = (const float*)d_in[9];
    const float* l2b    = (const float*)d_in[10];
    const float* ema0   = (const float*)d_in[11];
    const float* w3     = (const float*)d_in[12];
    const float* b3     = (const float*)d_in[13];
    const float* rg     = (const float*)d_in[14];
    float* out = (float*)d_out;

    // FULL (all ops at NTOK granularity) needs ~255.3 MB; SEGMENT needs ~180 MB (proven).
    const bool FULL = ws_size >= (size_t)255500000;
    const size_t YROWS = FULL ? (size_t)NTOK : (size_t)SEG_T;

    char* base = (char*)d_ws;
    size_t off = 0;
    auto alloc = [&](size_t bytes) -> void* {
        void* p = base + off;
        off += (bytes + 255) & ~(size_t)255;
        return p;
    };
    bf16* w1bf  = (bf16*)alloc((size_t)2 * DINNER * DMODEL * 2);
    bf16* w2bf  = (bf16*)alloc((size_t)NPROJP * DINNER * 2);
    bf16* w3bf  = (bf16*)alloc((size_t)DMODEL * DINNER * 2);
    bf16* xn    = (bf16*)alloc((size_t)NTOK * DMODEL * 2);
    bf16* ybuf  = (bf16*)alloc(YROWS * DINNER * 2);
    bf16* hf    = (bf16*)alloc(YROWS / 64 * NHEADS * 4096 * 2);
    bf16* xhalo = (bf16*)alloc((size_t)2 * 3 * DINNER * 2);
    float* cs   = (float*)alloc((size_t)6144 * 4);
    float* alp  = (float*)alloc((size_t)6144 * 4);
    float* dch  = (float*)alloc((size_t)6144 * 4);
    float* carry= (float*)alloc((size_t)48 * 4096 * 4);
    bf16* xp    = (bf16*)alloc((size_t)NTOK * NPROJ2 * 2);
    float* Aarr = (float*)alloc((size_t)NTOK * 24 * 4);
    float* invB = (float*)alloc((size_t)NTOK * 24 * 4);
    float* invC = (float*)alloc((size_t)NTOK * 24 * 4);
    bf16* xbuf  = ybuf;                    // pre-conv x aliases ybuf
    bf16* xc_all = (bf16*)d_out;           // xc for all tokens lives in d_out

    {
        int n1 = 2 * DINNER * DMODEL / 4, n2 = NPROJ * DINNER / 4, n3 = DMODEL * DINNER / 4;
        k_cvt<<<(n1 + 255) / 256, 256, 0, stream>>>(w1, w1bf, n1);
        k_cvt<<<(n2 + 255) / 256, 256, 0, stream>>>(w2, w2bf, n2);
        k_cvt<<<(n3 + 255) / 256, 256, 0, stream>>>(w3, w3bf, n3);
        int nz = (NPROJP - NPROJ) * DINNER;
        k_zero<<<(nz + 255) / 256, 256, 0, stream>>>(w2bf + (size_t)NPROJ * DINNER, nz);
    }

    const dim3 gPall(NPROJP / 128, NTOK / 128);          // 25 x 128

    if (FULL) {
        const dim3 gX16(DINNER / 128, NTOK / 128);       // 12 x 128
        const dim3 gO16(DMODEL / 128, NTOK / 128);       // 6 x 128
        k_rmsnorm<<<NTOK, 256, 0, stream>>>(hs, norm_w, xn);
        k_mgemm<bf16, 0><<<gX16, 256, 0, stream>>>(xn, w1bf, b1, xbuf,
                                                   NTOK, DINNER, DMODEL, nullptr, nullptr);
        k_conv8<<<NTOK, 192, 0, stream>>>(xbuf, cw, cbias, xc_all);
        k_mgemm<bf16, 2><<<gPall, 256, 0, stream>>>(xc_all, w2bf, b2, xp,
                                                    NTOK, NPROJ, DINNER, nullptr, nullptr);
        k_prep<<<NTOK * 24 / 4, 256, 0, stream>>>(xp, A_log, Aarr, invB, invC);
        k_surprise_all<<<6144, 256, 0, stream>>>(xp, xc_all, invB, cs);
        k_alpha<<<24, 256, 0, stream>>>(cs, ema0, l2ab, l2b, alp);

        k_chunk_all<<<6144, 256, 0, stream>>>(xp, xc_all, invB, invC, Aarr, alp,
                                              ybuf, hf, dch);
        k_mgemm<bf16, 0><<<gX16, 256, 0, stream>>>(xn, w1bf + (size_t)DINNER * DMODEL,
                                                   b1 + DINNER, xc_all,
                                                   NTOK, DINNER, DMODEL, nullptr, nullptr);
        k_scan_all<<<768, 256, 0, stream>>>(hf, dch);
        k_inter_all<<<6144, 256, 0, stream>>>(xp, invC, Aarr, alp, hf, xc_all, ybuf);
        k_mgemm<float, 1><<<gO16, 256, 0, stream>>>(ybuf, w3bf, b3, out,
                                                    NTOK, DMODEL, DINNER, hs, rg);
        return;
    }

    // ============ SEGMENT fallback (R9-proven structure, ~180 MB)
    const dim3 gX(DINNER / 128, SEG_T / 128);            // 12 x 32
    const dim3 gO(DMODEL / 128, SEG_T / 128);            // 6 x 32

    k_rmsnorm<<<NTOK, 256, 0, stream>>>(hs, norm_w, xn);
    for (int s = 0; s < NSEG; ++s) {
        size_t t0 = (size_t)s * SEG_T;
        int l0 = (int)(t0 & (L_SEQ - 1));
        bf16* xc = xc_all + t0 * DINNER;
        k_mgemm<bf16, 0><<<gX, 256, 0, stream>>>(xn + t0 * DMODEL, w1bf, b1, xbuf,
                                                 SEG_T, DINNER, DMODEL, nullptr, nullptr);
        k_save_halo<<<18, 256, 0, stream>>>(xbuf, xhalo + (size_t)((s + 1) & 1) * 3 * DINNER);
        k_conv_silu<<<dim3(DINNER / 256, SEG_T), 256, 0, stream>>>(
            xbuf, xhalo + (size_t)(s & 1) * 3 * DINNER, cw, cbias, xc, l0);
    }
    k_mgemm<bf16, 2><<<gPall, 256, 0, stream>>>(xc_all, w2bf, b2, xp,
                                                NTOK, NPROJ, DINNER, nullptr, nullptr);
    k_prep<<<NTOK * 24 / 4, 256, 0, stream>>>(xp, A_log, Aarr, invB, invC);
    k_surprise_all<<<6144, 256, 0, stream>>>(xp, xc_all, invB, cs);
    k_alpha<<<24, 256, 0, stream>>>(cs, ema0, l2ab, l2b, alp);

    for (int s = 0; s < NSEG; ++s) {
        size_t t0 = (size_t)s * SEG_T;
        int l0 = (int)(t0 & (L_SEQ - 1));
        int b  = (int)(t0 >> 13);
        const float* hseg = hs + t0 * DMODEL;
        bf16* xc = xc_all + t0 * DINNER;
        bf16* zseg = xc;                   // z overwrites dead xc region
        const bf16* xpS = xp + t0 * NPROJ2;
        const float* AarrS = Aarr + t0 * 24;
        const float* invBS = invB + t0 * 24;
        const float* invCS = invC + t0 * 24;
        k_chunk<<<NHEADS * 64, 256, 0, stream>>>(xpS, xc, invBS, invCS, AarrS, alp,
                                                 ybuf, hf, dch, b, l0);
        k_mgemm<bf16, 0><<<gX, 256, 0, stream>>>(xn + t0 * DMODEL,
                                                 w1bf + (size_t)DINNER * DMODEL,
                                                 b1 + DINNER, zseg,
                                                 SEG_T, DINNER, DMODEL, nullptr, nullptr);
        k_scan<<<384, 256, 0, stream>>>(hf, dch, carry, b, l0, 64);
        k_inter<<<NHEADS * 64, 256, 0, stream>>>(xpS, invCS, AarrS, alp, hf, zseg,
                                                 ybuf, b, l0);
        k_mgemm<float, 1><<<gO, 256, 0, stream>>>(ybuf, w3bf, b3, out + t0 * DMODEL,
                                                  SEG_T, DMODEL, DINNER, hseg, rg);
    }
}